// Round 1
// baseline (451.153 us; speedup 1.0000x reference)
//
#include <hip/hip_runtime.h>

#define DEVINL __device__ __forceinline__

typedef __attribute__((ext_vector_type(8))) short s8v;
typedef __attribute__((ext_vector_type(4))) float f4v;
typedef __attribute__((ext_vector_type(8))) __bf16 bf8v;

// Problem constants
static constexpr int SEQ = 2048;
static constexpr int DIM = 1024;
static constexpr int NH = 16;

DEVINL unsigned short f2bf(float f) {
  unsigned int u = __builtin_bit_cast(unsigned int, f);
  u += 0x7FFFu + ((u >> 16) & 1u);   // RNE
  return (unsigned short)(u >> 16);
}

DEVINL void gl_lds16(const void* g, void* l) {
  __builtin_amdgcn_global_load_lds((__attribute__((address_space(1))) void*)g,
                                   (__attribute__((address_space(3))) void*)l,
                                   16, 0, 0);
}

DEVINL f4v mfma16(s8v a, s8v b, f4v c) {
  return __builtin_amdgcn_mfma_f32_16x16x32_bf16(__builtin_bit_cast(bf8v, a),
                                                 __builtin_bit_cast(bf8v, b),
                                                 c, 0, 0, 0);
}

// ---- x: fp32 -> bf16, 8 elems/thread ----
__global__ __launch_bounds__(256) void k_cvt(const float* __restrict__ in,
                                             unsigned short* __restrict__ outp) {
  const int i = blockIdx.x * 256 + threadIdx.x;
  const f4v* p = (const f4v*)in + (size_t)i * 2;
  f4v a = p[0], b = p[1];
  s8v o;
  o[0] = (short)f2bf(a[0]); o[1] = (short)f2bf(a[1]);
  o[2] = (short)f2bf(a[2]); o[3] = (short)f2bf(a[3]);
  o[4] = (short)f2bf(b[0]); o[5] = (short)f2bf(b[1]);
  o[6] = (short)f2bf(b[2]); o[7] = (short)f2bf(b[3]);
  ((s8v*)outp)[i] = o;
}

// ---- weight transpose: fp32 [K][N] -> bf16 [N][K] (B^T form for GEMM) ----
__global__ __launch_bounds__(256) void k_twt(const float* __restrict__ w0, const float* __restrict__ w1,
                                             const float* __restrict__ w2, const float* __restrict__ w3,
                                             unsigned short* __restrict__ o0, unsigned short* __restrict__ o1,
                                             unsigned short* __restrict__ o2, unsigned short* __restrict__ o3) {
  __shared__ float tile[32][33];
  const float* w = blockIdx.z == 0 ? w0 : blockIdx.z == 1 ? w1 : blockIdx.z == 2 ? w2 : w3;
  unsigned short* o = blockIdx.z == 0 ? o0 : blockIdx.z == 1 ? o1 : blockIdx.z == 2 ? o2 : o3;
  const int r0 = blockIdx.y * 32, c0 = blockIdx.x * 32;
  const int tx = threadIdx.x & 31, ty = threadIdx.x >> 5;  // ty 0..7
#pragma unroll
  for (int i = 0; i < 32; i += 8) tile[ty + i][tx] = w[(r0 + ty + i) * DIM + c0 + tx];
  __syncthreads();
#pragma unroll
  for (int i = 0; i < 32; i += 8) o[(c0 + ty + i) * DIM + r0 + tx] = f2bf(tile[tx][ty + i]);
}

// ---- 128x128 bf16 GEMM mainloop (m97 structure): C = A[*,1024] x Bt[*,1024]^T ----
// LDS rows 128B, XOR-swizzle ((row&7)<<4) applied via pre-swizzled global source
// (linear gll dest) and swizzled ds_read (rule 21).
DEVINL void gemm_loop(const unsigned short* __restrict__ A, const unsigned short* __restrict__ Bt,
                      int m0, int n0, char* As, char* Bs, f4v acc[4][4]) {
  const int tid = threadIdx.x;
  const int lane = tid & 63;
  const int l15 = lane & 15, lg = lane >> 4;
  const int wm = (tid >> 6) >> 1, wn = (tid >> 6) & 1;
  for (int k0 = 0; k0 < 1024; k0 += 64) {
    __syncthreads();
#pragma unroll
    for (int i = 0; i < 4; ++i) {
      const int c = i * 256 + tid;
      const int row = c >> 3;
      const int csw = ((c & 7) ^ (row & 7)) * 8;
      gl_lds16(A + (size_t)(m0 + row) * 1024 + k0 + csw, As + c * 16);
      gl_lds16(Bt + (size_t)(n0 + row) * 1024 + k0 + csw, Bs + c * 16);
    }
    __syncthreads();
#pragma unroll
    for (int kk = 0; kk < 2; ++kk) {
      s8v af[4], bfr[4];
      const int kb2 = (kk * 32 + lg * 8) * 2;
#pragma unroll
      for (int mf = 0; mf < 4; ++mf) {
        const int row = wm * 64 + mf * 16 + l15;
        af[mf] = *(const s8v*)(As + row * 128 + (kb2 ^ ((row & 7) << 4)));
      }
#pragma unroll
      for (int nf = 0; nf < 4; ++nf) {
        const int row = wn * 64 + nf * 16 + l15;
        bfr[nf] = *(const s8v*)(Bs + row * 128 + (kb2 ^ ((row & 7) << 4)));
      }
#pragma unroll
      for (int mf = 0; mf < 4; ++mf)
#pragma unroll
        for (int nf = 0; nf < 4; ++nf) acc[mf][nf] = mfma16(af[mf], bfr[nf], acc[mf][nf]);
    }
  }
}

// ---- QKV projection: grid (64, 24): y/8 selects weight, y%8 selects n-block ----
__global__ __launch_bounds__(256) void k_qkv(const unsigned short* __restrict__ xb,
                                             const unsigned short* __restrict__ wqt,
                                             const unsigned short* __restrict__ wkt,
                                             const unsigned short* __restrict__ wvt,
                                             unsigned short* __restrict__ q,
                                             unsigned short* __restrict__ k,
                                             unsigned short* __restrict__ v) {
  __shared__ __align__(16) char smem[32768];
  const int m0 = blockIdx.x * 128;
  const int which = blockIdx.y >> 3;
  const int n0 = (blockIdx.y & 7) * 128;
  const unsigned short* Bt = which == 0 ? wqt : which == 1 ? wkt : wvt;
  unsigned short* C = which == 0 ? q : which == 1 ? k : v;
  f4v acc[4][4];
  f4v z = {0.f, 0.f, 0.f, 0.f};
#pragma unroll
  for (int a = 0; a < 4; ++a)
#pragma unroll
    for (int b = 0; b < 4; ++b) acc[a][b] = z;
  gemm_loop(xb, Bt, m0, n0, smem, smem + 16384, acc);
  const int lane = threadIdx.x & 63;
  const int l15 = lane & 15, lg = lane >> 4;
  const int wm = (threadIdx.x >> 6) >> 1, wn = (threadIdx.x >> 6) & 1;
#pragma unroll
  for (int mf = 0; mf < 4; ++mf)
#pragma unroll
    for (int nf = 0; nf < 4; ++nf)
#pragma unroll
      for (int r = 0; r < 4; ++r) {
        const int row = m0 + wm * 64 + mf * 16 + lg * 4 + r;   // D layout: row=(lane>>4)*4+r
        const int col = n0 + wn * 64 + nf * 16 + l15;          //           col=lane&15
        C[(size_t)row * 1024 + col] = f2bf(acc[mf][nf][r]);
      }
}

// ---- output projection + bias, fp32 out ----
__global__ __launch_bounds__(256) void k_oproj(const unsigned short* __restrict__ ctx,
                                               const unsigned short* __restrict__ wot,
                                               const float* __restrict__ bo,
                                               float* __restrict__ outp) {
  __shared__ __align__(16) char smem[32768];
  const int m0 = blockIdx.x * 128, n0 = blockIdx.y * 128;
  f4v acc[4][4];
  f4v z = {0.f, 0.f, 0.f, 0.f};
#pragma unroll
  for (int a = 0; a < 4; ++a)
#pragma unroll
    for (int b = 0; b < 4; ++b) acc[a][b] = z;
  gemm_loop(ctx, wot, m0, n0, smem, smem + 16384, acc);
  const int lane = threadIdx.x & 63;
  const int l15 = lane & 15, lg = lane >> 4;
  const int wm = (threadIdx.x >> 6) >> 1, wn = (threadIdx.x >> 6) & 1;
#pragma unroll
  for (int nf = 0; nf < 4; ++nf) {
    const int col = n0 + wn * 64 + nf * 16 + l15;
    const float bias = bo[col];
#pragma unroll
    for (int mf = 0; mf < 4; ++mf)
#pragma unroll
      for (int r = 0; r < 4; ++r) {
        const int row = m0 + wm * 64 + mf * 16 + lg * 4 + r;
        outp[(size_t)row * 1024 + col] = acc[mf][nf][r] + bias;
      }
  }
}

// ---- V -> V^T per head: [B,S,H,64] -> [B,H,64,S] so PV B-frag reads are contiguous-kv ----
__global__ __launch_bounds__(256) void k_tv(const unsigned short* __restrict__ v,
                                            unsigned short* __restrict__ vt) {
  __shared__ unsigned short tile[64][65];
  const int b = blockIdx.z, h = blockIdx.y, s0 = blockIdx.x * 64;
  const int t = threadIdx.x;
#pragma unroll
  for (int i = 0; i < 16; ++i) {
    const int s = i * 4 + (t >> 6), d = t & 63;
    tile[s][d] = v[(size_t)(b * SEQ + s0 + s) * 1024 + h * 64 + d];
  }
  __syncthreads();
#pragma unroll
  for (int i = 0; i < 16; ++i) {
    const int d = i * 4 + (t >> 6), s = t & 63;
    vt[(size_t)((b * NH + h) * 64 + d) * SEQ + s0 + s] = tile[s][d];
  }
}

// ---- causal flash attention: 4 waves x 16 q-rows, KVBLK=64, online softmax ----
__global__ __launch_bounds__(256) void k_attn(const unsigned short* __restrict__ q,
                                              const unsigned short* __restrict__ kg,
                                              const unsigned short* __restrict__ vt,
                                              unsigned short* __restrict__ ctx) {
  __shared__ __align__(16) char smem[24576];
  char* Ks = smem;          // [64 kv][64 d] bf16, swizzled
  char* Vs = smem + 8192;   // [64 d][64 kv] bf16 (V^T), swizzled
  char* Ps = smem + 16384;  // per-wave [16 q][64 kv] bf16, swizzled
  const int b = blockIdx.z, h = blockIdx.y, qb = blockIdx.x * 64;
  const int tid = threadIdx.x, lane = tid & 63, w = tid >> 6;
  const int l15 = lane & 15, lg = lane >> 4;

  // Q fragments: A-operand row = lane&15, k contiguous 8 per lane-group
  s8v qa[2];
  {
    const int row = qb + w * 16 + l15;
    const unsigned short* qp = q + (size_t)(b * SEQ + row) * 1024 + h * 64;
    qa[0] = *(const s8v*)(qp + lg * 8);
    qa[1] = *(const s8v*)(qp + 32 + lg * 8);
  }
  f4v z = {0.f, 0.f, 0.f, 0.f};
  f4v o[4];
  o[0] = z; o[1] = z; o[2] = z; o[3] = z;
  float mrow[4] = {-3e38f, -3e38f, -3e38f, -3e38f};
  float lrow[4] = {0.f, 0.f, 0.f, 0.f};

  const unsigned short* kbase = kg + (size_t)b * SEQ * 1024 + h * 64;
  const unsigned short* vbase = vt + (size_t)((b * NH + h) * 64) * SEQ;

  const int nt = qb / 64 + 1;
  for (int t = 0; t < nt; ++t) {
    const int kv0 = t * 64;
    __syncthreads();
#pragma unroll
    for (int i = 0; i < 2; ++i) {
      const int c = i * 256 + tid;
      const int row = c >> 3;
      const int csw = ((c & 7) ^ (row & 7)) * 8;  // pre-swizzled source, linear LDS dest
      gl_lds16(kbase + (size_t)(kv0 + row) * 1024 + csw, Ks + c * 16);
      gl_lds16(vbase + (size_t)row * SEQ + kv0 + csw, Vs + c * 16);
    }
    __syncthreads();

    // QK^T: B-operand = K (col=kv=lane&15 row of K_lds, k=d contiguous)
    f4v sc[4];
    sc[0] = z; sc[1] = z; sc[2] = z; sc[3] = z;
#pragma unroll
    for (int kk = 0; kk < 2; ++kk) {
      const int kb2 = (kk * 32 + lg * 8) * 2;
#pragma unroll
      for (int nf = 0; nf < 4; ++nf) {
        const int row = nf * 16 + l15;
        const s8v kf = *(const s8v*)(Ks + row * 128 + (kb2 ^ ((row & 7) << 4)));
        sc[nf] = mfma16(qa[kk], kf, sc[nf]);
      }
    }

    const bool diag = (t == nt - 1);
    float p[4][4];
    float tmax[4] = {-3e38f, -3e38f, -3e38f, -3e38f};
#pragma unroll
    for (int nf = 0; nf < 4; ++nf)
#pragma unroll
      for (int jj = 0; jj < 4; ++jj) {
        float s = sc[nf][jj] * 0.125f;  // 1/sqrt(64)
        if (diag) {
          const int kvg = kv0 + nf * 16 + l15;
          const int qg = qb + w * 16 + lg * 4 + jj;
          if (kvg > qg) s = -3e38f;
        }
        p[nf][jj] = s;
        tmax[jj] = fmaxf(tmax[jj], s);
      }
    float corr[4];
#pragma unroll
    for (int jj = 0; jj < 4; ++jj) {
      float vv = tmax[jj];
      vv = fmaxf(vv, __shfl_xor(vv, 1));
      vv = fmaxf(vv, __shfl_xor(vv, 2));
      vv = fmaxf(vv, __shfl_xor(vv, 4));
      vv = fmaxf(vv, __shfl_xor(vv, 8));
      const float mnew = fmaxf(mrow[jj], vv);
      corr[jj] = __expf(mrow[jj] - mnew);
      mrow[jj] = mnew;
    }
    float rsum[4] = {0.f, 0.f, 0.f, 0.f};
#pragma unroll
    for (int nf = 0; nf < 4; ++nf)
#pragma unroll
      for (int jj = 0; jj < 4; ++jj) {
        const float e = __expf(p[nf][jj] - mrow[jj]);
        rsum[jj] += e;
        const int prow = lg * 4 + jj;       // D layout row
        const int pcol = nf * 16 + l15;     // D layout col
        *(unsigned short*)(Ps + w * 2048 + prow * 128 + ((pcol * 2) ^ ((prow & 7) << 4))) = f2bf(e);
      }
#pragma unroll
    for (int jj = 0; jj < 4; ++jj) {
      float vv = rsum[jj];
      vv += __shfl_xor(vv, 1);
      vv += __shfl_xor(vv, 2);
      vv += __shfl_xor(vv, 4);
      vv += __shfl_xor(vv, 8);
      lrow[jj] = lrow[jj] * corr[jj] + vv;
    }
#pragma unroll
    for (int df = 0; df < 4; ++df) {
      o[df][0] *= corr[0]; o[df][1] *= corr[1];
      o[df][2] *= corr[2]; o[df][3] *= corr[3];
    }

    // fence: P_lds writes must complete before cross-lane A-frag reads (rule 18)
    asm volatile("s_waitcnt lgkmcnt(0)" ::: "memory");
    __builtin_amdgcn_sched_barrier(0);

    // PV: A = P (row=q=lane&15, k=kv contiguous), B = V^T rows (col=d=lane&15)
#pragma unroll
    for (int kk = 0; kk < 2; ++kk) {
      const int kb2 = (kk * 32 + lg * 8) * 2;
      const s8v pa = *(const s8v*)(Ps + w * 2048 + l15 * 128 + (kb2 ^ ((l15 & 7) << 4)));
#pragma unroll
      for (int df = 0; df < 4; ++df) {
        const int row = df * 16 + l15;
        const s8v vf = *(const s8v*)(Vs + row * 128 + (kb2 ^ ((row & 7) << 4)));
        o[df] = mfma16(pa, vf, o[df]);
      }
    }
  }

#pragma unroll
  for (int df = 0; df < 4; ++df)
#pragma unroll
    for (int jj = 0; jj < 4; ++jj) {
      const int row = qb + w * 16 + lg * 4 + jj;
      const int col = h * 64 + df * 16 + l15;
      ctx[(size_t)(b * SEQ + row) * 1024 + col] = f2bf(o[df][jj] / lrow[jj]);
    }
}

extern "C" void kernel_launch(void* const* d_in, const int* in_sizes, int n_in,
                              void* d_out, int out_size, void* d_ws, size_t ws_size,
                              hipStream_t stream) {
  (void)in_sizes; (void)n_in; (void)out_size; (void)ws_size;
  const float* x = (const float*)d_in[0];
  const float* wq = (const float*)d_in[1];
  const float* wk = (const float*)d_in[2];
  const float* wv = (const float*)d_in[3];
  const float* wo = (const float*)d_in[4];
  const float* bo = (const float*)d_in[5];
  float* outp = (float*)d_out;
  char* ws = (char*)d_ws;
  const size_t MB = 1ull << 20;
  unsigned short* xb  = (unsigned short*)(ws + 0 * MB);   // 16 MiB [8192,1024] bf16
  unsigned short* wqt = (unsigned short*)(ws + 16 * MB);  // 2 MiB each, transposed bf16
  unsigned short* wkt = (unsigned short*)(ws + 18 * MB);
  unsigned short* wvt = (unsigned short*)(ws + 20 * MB);
  unsigned short* wot = (unsigned short*)(ws + 22 * MB);
  unsigned short* qb_ = (unsigned short*)(ws + 24 * MB);  // 16 MiB each
  unsigned short* kb_ = (unsigned short*)(ws + 40 * MB);
  unsigned short* vb_ = (unsigned short*)(ws + 56 * MB);
  unsigned short* vtb = (unsigned short*)(ws + 72 * MB);  // V^T [B,H,64,S]
  unsigned short* ctx = (unsigned short*)(ws + 88 * MB);  // 16 MiB

  k_cvt<<<4096, 256, 0, stream>>>(x, xb);
  k_twt<<<dim3(32, 32, 4), 256, 0, stream>>>(wq, wk, wv, wo, wqt, wkt, wvt, wot);
  k_qkv<<<dim3(64, 24), 256, 0, stream>>>(xb, wqt, wkt, wvt, qb_, kb_, vb_);
  k_tv<<<dim3(32, 16, 4), 256, 0, stream>>>(vb_, vtb);
  k_attn<<<dim3(32, 16, 4), 256, 0, stream>>>(qb_, kb_, vtb, ctx);
  k_oproj<<<dim3(64, 8), 256, 0, stream>>>(ctx, wot, bo, outp);
}

// Round 2
// 323.939 us; speedup vs baseline: 1.3927x; 1.3927x over previous
//
#include <hip/hip_runtime.h>

#define DEVINL __device__ __forceinline__

typedef __attribute__((ext_vector_type(8))) short s8v;
typedef __attribute__((ext_vector_type(4))) float f4v;
typedef __attribute__((ext_vector_type(8))) __bf16 bf8v;

// Problem constants
static constexpr int SEQ = 2048;
static constexpr int DIM = 1024;
static constexpr int NH = 16;

DEVINL unsigned short f2bf(float f) {
  unsigned int u = __builtin_bit_cast(unsigned int, f);
  u += 0x7FFFu + ((u >> 16) & 1u);   // RNE
  return (unsigned short)(u >> 16);
}

DEVINL void gl_lds16(const void* g, void* l) {
  __builtin_amdgcn_global_load_lds((__attribute__((address_space(1))) void*)g,
                                   (__attribute__((address_space(3))) void*)l,
                                   16, 0, 0);
}

DEVINL f4v mfma16(s8v a, s8v b, f4v c) {
  return __builtin_amdgcn_mfma_f32_16x16x32_bf16(__builtin_bit_cast(bf8v, a),
                                                 __builtin_bit_cast(bf8v, b),
                                                 c, 0, 0, 0);
}

// ---- x: fp32 -> bf16, 8 elems/thread ----
__global__ __launch_bounds__(256) void k_cvt(const float* __restrict__ in,
                                             unsigned short* __restrict__ outp) {
  const int i = blockIdx.x * 256 + threadIdx.x;
  const f4v* p = (const f4v*)in + (size_t)i * 2;
  f4v a = p[0], b = p[1];
  s8v o;
  o[0] = (short)f2bf(a[0]); o[1] = (short)f2bf(a[1]);
  o[2] = (short)f2bf(a[2]); o[3] = (short)f2bf(a[3]);
  o[4] = (short)f2bf(b[0]); o[5] = (short)f2bf(b[1]);
  o[6] = (short)f2bf(b[2]); o[7] = (short)f2bf(b[3]);
  ((s8v*)outp)[i] = o;
}

// ---- weight transpose: fp32 [K][N] -> bf16 [N][K] (B^T form for GEMM) ----
__global__ __launch_bounds__(256) void k_twt(const float* __restrict__ w0, const float* __restrict__ w1,
                                             const float* __restrict__ w2, const float* __restrict__ w3,
                                             unsigned short* __restrict__ o0, unsigned short* __restrict__ o1,
                                             unsigned short* __restrict__ o2, unsigned short* __restrict__ o3) {
  __shared__ float tile[32][33];
  const float* w = blockIdx.z == 0 ? w0 : blockIdx.z == 1 ? w1 : blockIdx.z == 2 ? w2 : w3;
  unsigned short* o = blockIdx.z == 0 ? o0 : blockIdx.z == 1 ? o1 : blockIdx.z == 2 ? o2 : o3;
  const int r0 = blockIdx.y * 32, c0 = blockIdx.x * 32;
  const int tx = threadIdx.x & 31, ty = threadIdx.x >> 5;  // ty 0..7
#pragma unroll
  for (int i = 0; i < 32; i += 8) tile[ty + i][tx] = w[(r0 + ty + i) * DIM + c0 + tx];
  __syncthreads();
#pragma unroll
  for (int i = 0; i < 32; i += 8) o[(c0 + ty + i) * DIM + r0 + tx] = f2bf(tile[tx][ty + i]);
}

// ---- 128x128 bf16 GEMM mainloop (m97 structure): C = A[*,1024] x Bt[*,1024]^T ----
DEVINL void gemm_loop(const unsigned short* __restrict__ A, const unsigned short* __restrict__ Bt,
                      int m0, int n0, char* As, char* Bs, f4v acc[4][4]) {
  const int tid = threadIdx.x;
  const int lane = tid & 63;
  const int l15 = lane & 15, lg = lane >> 4;
  const int wm = (tid >> 6) >> 1, wn = (tid >> 6) & 1;
  for (int k0 = 0; k0 < 1024; k0 += 64) {
    __syncthreads();
#pragma unroll
    for (int i = 0; i < 4; ++i) {
      const int c = i * 256 + tid;
      const int row = c >> 3;
      const int csw = ((c & 7) ^ (row & 7)) * 8;
      gl_lds16(A + (size_t)(m0 + row) * 1024 + k0 + csw, As + c * 16);
      gl_lds16(Bt + (size_t)(n0 + row) * 1024 + k0 + csw, Bs + c * 16);
    }
    __syncthreads();
#pragma unroll
    for (int kk = 0; kk < 2; ++kk) {
      s8v af[4], bfr[4];
      const int kb2 = (kk * 32 + lg * 8) * 2;
#pragma unroll
      for (int mf = 0; mf < 4; ++mf) {
        const int row = wm * 64 + mf * 16 + l15;
        af[mf] = *(const s8v*)(As + row * 128 + (kb2 ^ ((row & 7) << 4)));
      }
#pragma unroll
      for (int nf = 0; nf < 4; ++nf) {
        const int row = wn * 64 + nf * 16 + l15;
        bfr[nf] = *(const s8v*)(Bs + row * 128 + (kb2 ^ ((row & 7) << 4)));
      }
#pragma unroll
      for (int mf = 0; mf < 4; ++mf)
#pragma unroll
        for (int nf = 0; nf < 4; ++nf) acc[mf][nf] = mfma16(af[mf], bfr[nf], acc[mf][nf]);
    }
  }
}

// ---- QKV projection: grid (64, 24): y/8 selects weight, y%8 selects n-block ----
__global__ __launch_bounds__(256) void k_qkv(const unsigned short* __restrict__ xb,
                                             const unsigned short* __restrict__ wqt,
                                             const unsigned short* __restrict__ wkt,
                                             const unsigned short* __restrict__ wvt,
                                             unsigned short* __restrict__ q,
                                             unsigned short* __restrict__ k,
                                             unsigned short* __restrict__ v) {
  __shared__ __align__(16) char smem[32768];
  const int m0 = blockIdx.x * 128;
  const int which = blockIdx.y >> 3;
  const int n0 = (blockIdx.y & 7) * 128;
  const unsigned short* Bt = which == 0 ? wqt : which == 1 ? wkt : wvt;
  unsigned short* C = which == 0 ? q : which == 1 ? k : v;
  f4v acc[4][4];
  f4v z = {0.f, 0.f, 0.f, 0.f};
#pragma unroll
  for (int a = 0; a < 4; ++a)
#pragma unroll
    for (int b = 0; b < 4; ++b) acc[a][b] = z;
  gemm_loop(xb, Bt, m0, n0, smem, smem + 16384, acc);
  const int lane = threadIdx.x & 63;
  const int l15 = lane & 15, lg = lane >> 4;
  const int wm = (threadIdx.x >> 6) >> 1, wn = (threadIdx.x >> 6) & 1;
#pragma unroll
  for (int mf = 0; mf < 4; ++mf)
#pragma unroll
    for (int nf = 0; nf < 4; ++nf)
#pragma unroll
      for (int r = 0; r < 4; ++r) {
        const int row = m0 + wm * 64 + mf * 16 + lg * 4 + r;
        const int col = n0 + wn * 64 + nf * 16 + l15;
        C[(size_t)row * 1024 + col] = f2bf(acc[mf][nf][r]);
      }
}

// ---- output projection + bias, fp32 out ----
__global__ __launch_bounds__(256) void k_oproj(const unsigned short* __restrict__ ctx,
                                               const unsigned short* __restrict__ wot,
                                               const float* __restrict__ bo,
                                               float* __restrict__ outp) {
  __shared__ __align__(16) char smem[32768];
  const int m0 = blockIdx.x * 128, n0 = blockIdx.y * 128;
  f4v acc[4][4];
  f4v z = {0.f, 0.f, 0.f, 0.f};
#pragma unroll
  for (int a = 0; a < 4; ++a)
#pragma unroll
    for (int b = 0; b < 4; ++b) acc[a][b] = z;
  gemm_loop(ctx, wot, m0, n0, smem, smem + 16384, acc);
  const int lane = threadIdx.x & 63;
  const int l15 = lane & 15, lg = lane >> 4;
  const int wm = (threadIdx.x >> 6) >> 1, wn = (threadIdx.x >> 6) & 1;
#pragma unroll
  for (int nf = 0; nf < 4; ++nf) {
    const int col = n0 + wn * 64 + nf * 16 + l15;
    const float bias = bo[col];
#pragma unroll
    for (int mf = 0; mf < 4; ++mf)
#pragma unroll
      for (int r = 0; r < 4; ++r) {
        const int row = m0 + wm * 64 + mf * 16 + lg * 4 + r;
        outp[(size_t)row * 1024 + col] = acc[mf][nf][r] + bias;
      }
  }
}

// ---- V -> V^T per head: [B,S,H,64] -> [B,H,64,S] ----
__global__ __launch_bounds__(256) void k_tv(const unsigned short* __restrict__ v,
                                            unsigned short* __restrict__ vt) {
  __shared__ unsigned short tile[64][65];
  const int b = blockIdx.z, h = blockIdx.y, s0 = blockIdx.x * 64;
  const int t = threadIdx.x;
#pragma unroll
  for (int i = 0; i < 16; ++i) {
    const int s = i * 4 + (t >> 6), d = t & 63;
    tile[s][d] = v[(size_t)(b * SEQ + s0 + s) * 1024 + h * 64 + d];
  }
  __syncthreads();
#pragma unroll
  for (int i = 0; i < 16; ++i) {
    const int d = i * 4 + (t >> 6), s = t & 63;
    vt[(size_t)((b * NH + h) * 64 + d) * SEQ + s0 + s] = tile[s][d];
  }
}

// ---- stage one 64-kv tile of K and V^T into LDS (swizzled source, linear dest) ----
DEVINL void stage_kv(const unsigned short* __restrict__ kbase,
                     const unsigned short* __restrict__ vbase,
                     int kv0, char* Ks, char* Vs, int tid) {
#pragma unroll
  for (int i = 0; i < 2; ++i) {
    const int c = i * 256 + tid;
    const int row = c >> 3;
    const int csw = ((c & 7) ^ (row & 7)) * 8;
    gl_lds16(kbase + (size_t)(kv0 + row) * 1024 + csw, Ks + c * 16);
    gl_lds16(vbase + (size_t)row * SEQ + kv0 + csw, Vs + c * 16);
  }
}

// ---- causal flash attention: 4 waves x 16 q-rows, KVBLK=64 ----
// Work-balanced: block processes q-blocks (pair, 31-pair) -> exactly 33 KV-tiles each.
// Double-buffered K/V staging: prefetch tile t+1 while computing tile t.
__global__ __launch_bounds__(256) void k_attn(const unsigned short* __restrict__ q,
                                              const unsigned short* __restrict__ kg,
                                              const unsigned short* __restrict__ vt,
                                              unsigned short* __restrict__ ctx) {
  __shared__ __align__(16) char smem[40960];
  // [0..8K) K buf0, [8K..16K) K buf1, [16K..24K) V buf0, [24K..32K) V buf1, [32K..40K) P
  char* Ps = smem + 32768;
  const int b = blockIdx.z, h = blockIdx.y, pair = blockIdx.x;
  const int tid = threadIdx.x, lane = tid & 63, w = tid >> 6;
  const int l15 = lane & 15, lg = lane >> 4;

  const unsigned short* kbase = kg + (size_t)b * SEQ * 1024 + h * 64;
  const unsigned short* vbase = vt + (size_t)((b * NH + h) * 64) * SEQ;
  const float SCL = 0.125f * 1.44269504f;  // 1/sqrt(64) * log2(e); use exp2
  const f4v z = {0.f, 0.f, 0.f, 0.f};

  for (int seg = 0; seg < 2; ++seg) {
    const int qi = seg == 0 ? pair : 31 - pair;
    const int qbb = qi * 64;
    // Q fragments for this segment
    s8v qa0, qa1;
    {
      const int row = qbb + w * 16 + l15;
      const unsigned short* qp = q + (size_t)(b * SEQ + row) * 1024 + h * 64;
      qa0 = *(const s8v*)(qp + lg * 8);
      qa1 = *(const s8v*)(qp + 32 + lg * 8);
    }
    f4v o[4];
    o[0] = z; o[1] = z; o[2] = z; o[3] = z;
    float mrow[4] = {-3e38f, -3e38f, -3e38f, -3e38f};
    float lrow[4] = {0.f, 0.f, 0.f, 0.f};
    const int nt = qi + 1;

    __syncthreads();  // previous segment's buffer reads complete
    stage_kv(kbase, vbase, 0, smem, smem + 16384, tid);

    for (int t = 0; t < nt; ++t) {
      const int kv0 = t * 64;
      char* Ks = smem + (t & 1) * 8192;
      char* Vs = smem + 16384 + (t & 1) * 8192;
      __syncthreads();  // drains vmcnt -> current buffers ready
      if (t + 1 < nt)
        stage_kv(kbase, vbase, kv0 + 64, smem + ((t + 1) & 1) * 8192,
                 smem + 16384 + ((t + 1) & 1) * 8192, tid);

      // QK^T
      f4v sc[4];
      sc[0] = z; sc[1] = z; sc[2] = z; sc[3] = z;
#pragma unroll
      for (int kk = 0; kk < 2; ++kk) {
        const int kb2 = (kk * 32 + lg * 8) * 2;
        const s8v qa = kk == 0 ? qa0 : qa1;
#pragma unroll
        for (int nf = 0; nf < 4; ++nf) {
          const int row = nf * 16 + l15;
          const s8v kf = *(const s8v*)(Ks + row * 128 + (kb2 ^ ((row & 7) << 4)));
          sc[nf] = mfma16(qa, kf, sc[nf]);
        }
      }

      // scale (+ causal mask only on diagonal-crossing tiles), track row max
      const bool needmask = (kv0 + 63 > qbb + w * 16);
      float p[4][4];
      float tmax[4] = {-3e38f, -3e38f, -3e38f, -3e38f};
#pragma unroll
      for (int nf = 0; nf < 4; ++nf)
#pragma unroll
        for (int jj = 0; jj < 4; ++jj) {
          float s = sc[nf][jj] * SCL;
          if (needmask) {
            const int kvg = kv0 + nf * 16 + l15;
            const int qg = qbb + w * 16 + lg * 4 + jj;
            if (kvg > qg) s = -3e38f;
          }
          p[nf][jj] = s;
          tmax[jj] = fmaxf(tmax[jj], s);
        }
      float corr[4];
#pragma unroll
      for (int jj = 0; jj < 4; ++jj) {
        float vv = tmax[jj];
        vv = fmaxf(vv, __shfl_xor(vv, 1));
        vv = fmaxf(vv, __shfl_xor(vv, 2));
        vv = fmaxf(vv, __shfl_xor(vv, 4));
        vv = fmaxf(vv, __shfl_xor(vv, 8));
        const float mnew = fmaxf(mrow[jj], vv);
        corr[jj] = exp2f(mrow[jj] - mnew);
        mrow[jj] = mnew;
      }
      float rsum[4] = {0.f, 0.f, 0.f, 0.f};
#pragma unroll
      for (int nf = 0; nf < 4; ++nf)
#pragma unroll
        for (int jj = 0; jj < 4; ++jj) {
          const float e = exp2f(p[nf][jj] - mrow[jj]);
          rsum[jj] += e;
          const int prow = lg * 4 + jj;
          const int pcol = nf * 16 + l15;
          *(unsigned short*)(Ps + w * 2048 + prow * 128 + ((pcol * 2) ^ ((prow & 7) << 4))) = f2bf(e);
        }
#pragma unroll
      for (int jj = 0; jj < 4; ++jj) {
        float vv = rsum[jj];
        vv += __shfl_xor(vv, 1);
        vv += __shfl_xor(vv, 2);
        vv += __shfl_xor(vv, 4);
        vv += __shfl_xor(vv, 8);
        lrow[jj] = lrow[jj] * corr[jj] + vv;
      }
#pragma unroll
      for (int df = 0; df < 4; ++df) {
        o[df][0] *= corr[0]; o[df][1] *= corr[1];
        o[df][2] *= corr[2]; o[df][3] *= corr[3];
      }

      // fence: P_lds writes must land before cross-lane A-frag reads (rule 18)
      asm volatile("s_waitcnt lgkmcnt(0)" ::: "memory");
      __builtin_amdgcn_sched_barrier(0);

      // PV
#pragma unroll
      for (int kk = 0; kk < 2; ++kk) {
        const int kb2 = (kk * 32 + lg * 8) * 2;
        const s8v pa = *(const s8v*)(Ps + w * 2048 + l15 * 128 + (kb2 ^ ((l15 & 7) << 4)));
#pragma unroll
        for (int df = 0; df < 4; ++df) {
          const int row = df * 16 + l15;
          const s8v vf = *(const s8v*)(Vs + row * 128 + (kb2 ^ ((row & 7) << 4)));
          o[df] = mfma16(pa, vf, o[df]);
        }
      }
    }

    // epilogue for this segment
#pragma unroll
    for (int jj = 0; jj < 4; ++jj) lrow[jj] = 1.f / lrow[jj];
#pragma unroll
    for (int df = 0; df < 4; ++df)
#pragma unroll
      for (int jj = 0; jj < 4; ++jj) {
        const int row = qbb + w * 16 + lg * 4 + jj;
        const int col = h * 64 + df * 16 + l15;
        ctx[(size_t)(b * SEQ + row) * 1024 + col] = f2bf(o[df][jj] * lrow[jj]);
      }
  }
}

extern "C" void kernel_launch(void* const* d_in, const int* in_sizes, int n_in,
                              void* d_out, int out_size, void* d_ws, size_t ws_size,
                              hipStream_t stream) {
  (void)in_sizes; (void)n_in; (void)out_size; (void)ws_size;
  const float* x = (const float*)d_in[0];
  const float* wq = (const float*)d_in[1];
  const float* wk = (const float*)d_in[2];
  const float* wv = (const float*)d_in[3];
  const float* wo = (const float*)d_in[4];
  const float* bo = (const float*)d_in[5];
  float* outp = (float*)d_out;
  char* ws = (char*)d_ws;
  const size_t MB = 1ull << 20;
  unsigned short* xb  = (unsigned short*)(ws + 0 * MB);
  unsigned short* wqt = (unsigned short*)(ws + 16 * MB);
  unsigned short* wkt = (unsigned short*)(ws + 18 * MB);
  unsigned short* wvt = (unsigned short*)(ws + 20 * MB);
  unsigned short* wot = (unsigned short*)(ws + 22 * MB);
  unsigned short* qb_ = (unsigned short*)(ws + 24 * MB);
  unsigned short* kb_ = (unsigned short*)(ws + 40 * MB);
  unsigned short* vb_ = (unsigned short*)(ws + 56 * MB);
  unsigned short* vtb = (unsigned short*)(ws + 72 * MB);
  unsigned short* ctx = (unsigned short*)(ws + 88 * MB);

  k_cvt<<<4096, 256, 0, stream>>>(x, xb);
  k_twt<<<dim3(32, 32, 4), 256, 0, stream>>>(wq, wk, wv, wo, wqt, wkt, wvt, wot);
  k_qkv<<<dim3(64, 24), 256, 0, stream>>>(xb, wqt, wkt, wvt, qb_, kb_, vb_);
  k_tv<<<dim3(32, 16, 4), 256, 0, stream>>>(vb_, vtb);
  k_attn<<<dim3(16, 16, 4), 256, 0, stream>>>(qb_, kb_, vtb, ctx);
  k_oproj<<<dim3(64, 8), 256, 0, stream>>>(ctx, wot, bo, outp);
}

// Round 3
// 260.610 us; speedup vs baseline: 1.7311x; 1.2430x over previous
//
#include <hip/hip_runtime.h>

#define DEVINL __device__ __forceinline__

typedef __attribute__((ext_vector_type(8))) short s8v;
typedef __attribute__((ext_vector_type(4))) float f4v;
typedef __attribute__((ext_vector_type(16))) float f16v;
typedef __attribute__((ext_vector_type(8))) __bf16 bf8v;
typedef __attribute__((ext_vector_type(4))) unsigned int u4v;

// Problem constants
static constexpr int SEQ = 2048;
static constexpr int DIM = 1024;
static constexpr int NH = 16;

DEVINL unsigned short f2bf(float f) {
  unsigned int u = __builtin_bit_cast(unsigned int, f);
  u += 0x7FFFu + ((u >> 16) & 1u);   // RNE
  return (unsigned short)(u >> 16);
}

DEVINL void gl_lds16(const void* g, void* l) {
  __builtin_amdgcn_global_load_lds((__attribute__((address_space(1))) void*)g,
                                   (__attribute__((address_space(3))) void*)l,
                                   16, 0, 0);
}

DEVINL f4v mfma16(s8v a, s8v b, f4v c) {
  return __builtin_amdgcn_mfma_f32_16x16x32_bf16(__builtin_bit_cast(bf8v, a),
                                                 __builtin_bit_cast(bf8v, b),
                                                 c, 0, 0, 0);
}

DEVINL f16v mfma32(s8v a, s8v b, f16v c) {
  return __builtin_amdgcn_mfma_f32_32x32x16_bf16(__builtin_bit_cast(bf8v, a),
                                                 __builtin_bit_cast(bf8v, b),
                                                 c, 0, 0, 0);
}

DEVINL unsigned cvtpk(float lo, float hi) {
  unsigned r;
  asm("v_cvt_pk_bf16_f32 %0, %1, %2" : "=v"(r) : "v"(lo), "v"(hi));
  return r;
}

DEVINL void plswap(unsigned& a, unsigned& b) {
#if __has_builtin(__builtin_amdgcn_permlane32_swap)
  typedef int i2v __attribute__((ext_vector_type(2)));
  i2v r = __builtin_amdgcn_permlane32_swap((int)a, (int)b, false, false);
  a = (unsigned)r[0]; b = (unsigned)r[1];
#else
  asm volatile("v_permlane32_swap_b32 %0, %1" : "+v"(a), "+v"(b));
#endif
}

DEVINL s8v mkfrag(unsigned w0, unsigned w1, unsigned w2, unsigned w3) {
  u4v t = {w0, w1, w2, w3};
  return __builtin_bit_cast(s8v, t);
}

// ---- x: fp32 -> bf16, 8 elems/thread ----
__global__ __launch_bounds__(256) void k_cvt(const float* __restrict__ in,
                                             unsigned short* __restrict__ outp) {
  const int i = blockIdx.x * 256 + threadIdx.x;
  const f4v* p = (const f4v*)in + (size_t)i * 2;
  f4v a = p[0], b = p[1];
  s8v o;
  o[0] = (short)f2bf(a[0]); o[1] = (short)f2bf(a[1]);
  o[2] = (short)f2bf(a[2]); o[3] = (short)f2bf(a[3]);
  o[4] = (short)f2bf(b[0]); o[5] = (short)f2bf(b[1]);
  o[6] = (short)f2bf(b[2]); o[7] = (short)f2bf(b[3]);
  ((s8v*)outp)[i] = o;
}

// ---- weight transpose: fp32 [K][N] -> bf16 [N][K] ----
__global__ __launch_bounds__(256) void k_twt(const float* __restrict__ w0, const float* __restrict__ w1,
                                             const float* __restrict__ w2, const float* __restrict__ w3,
                                             unsigned short* __restrict__ o0, unsigned short* __restrict__ o1,
                                             unsigned short* __restrict__ o2, unsigned short* __restrict__ o3) {
  __shared__ float tile[32][33];
  const float* w = blockIdx.z == 0 ? w0 : blockIdx.z == 1 ? w1 : blockIdx.z == 2 ? w2 : w3;
  unsigned short* o = blockIdx.z == 0 ? o0 : blockIdx.z == 1 ? o1 : blockIdx.z == 2 ? o2 : o3;
  const int r0 = blockIdx.y * 32, c0 = blockIdx.x * 32;
  const int tx = threadIdx.x & 31, ty = threadIdx.x >> 5;
#pragma unroll
  for (int i = 0; i < 32; i += 8) tile[ty + i][tx] = w[(r0 + ty + i) * DIM + c0 + tx];
  __syncthreads();
#pragma unroll
  for (int i = 0; i < 32; i += 8) o[(c0 + ty + i) * DIM + r0 + tx] = f2bf(tile[tx][ty + i]);
}

// ---- 128x128 bf16 GEMM mainloop (m97 structure) ----
DEVINL void gemm_loop(const unsigned short* __restrict__ A, const unsigned short* __restrict__ Bt,
                      int m0, int n0, char* As, char* Bs, f4v acc[4][4]) {
  const int tid = threadIdx.x;
  const int lane = tid & 63;
  const int l15 = lane & 15, lg = lane >> 4;
  const int wm = (tid >> 6) >> 1, wn = (tid >> 6) & 1;
  for (int k0 = 0; k0 < 1024; k0 += 64) {
    __syncthreads();
#pragma unroll
    for (int i = 0; i < 4; ++i) {
      const int c = i * 256 + tid;
      const int row = c >> 3;
      const int csw = ((c & 7) ^ (row & 7)) * 8;
      gl_lds16(A + (size_t)(m0 + row) * 1024 + k0 + csw, As + c * 16);
      gl_lds16(Bt + (size_t)(n0 + row) * 1024 + k0 + csw, Bs + c * 16);
    }
    __syncthreads();
#pragma unroll
    for (int kk = 0; kk < 2; ++kk) {
      s8v af[4], bfr[4];
      const int kb2 = (kk * 32 + lg * 8) * 2;
#pragma unroll
      for (int mf = 0; mf < 4; ++mf) {
        const int row = wm * 64 + mf * 16 + l15;
        af[mf] = *(const s8v*)(As + row * 128 + (kb2 ^ ((row & 7) << 4)));
      }
#pragma unroll
      for (int nf = 0; nf < 4; ++nf) {
        const int row = wn * 64 + nf * 16 + l15;
        bfr[nf] = *(const s8v*)(Bs + row * 128 + (kb2 ^ ((row & 7) << 4)));
      }
#pragma unroll
      for (int mf = 0; mf < 4; ++mf)
#pragma unroll
        for (int nf = 0; nf < 4; ++nf) acc[mf][nf] = mfma16(af[mf], bfr[nf], acc[mf][nf]);
    }
  }
}

// ---- QKV projection; Q output pre-scaled by 1/sqrt(64)*log2(e) for exp2-domain attn ----
__global__ __launch_bounds__(256) void k_qkv(const unsigned short* __restrict__ xb,
                                             const unsigned short* __restrict__ wqt,
                                             const unsigned short* __restrict__ wkt,
                                             const unsigned short* __restrict__ wvt,
                                             unsigned short* __restrict__ q,
                                             unsigned short* __restrict__ k,
                                             unsigned short* __restrict__ v) {
  __shared__ __align__(16) char smem[32768];
  const int m0 = blockIdx.x * 128;
  const int which = blockIdx.y >> 3;
  const int n0 = (blockIdx.y & 7) * 128;
  const unsigned short* Bt = which == 0 ? wqt : which == 1 ? wkt : wvt;
  unsigned short* C = which == 0 ? q : which == 1 ? k : v;
  const float oscale = which == 0 ? 0.125f * 1.44269504f : 1.0f;
  f4v acc[4][4];
  f4v z = {0.f, 0.f, 0.f, 0.f};
#pragma unroll
  for (int a = 0; a < 4; ++a)
#pragma unroll
    for (int b = 0; b < 4; ++b) acc[a][b] = z;
  gemm_loop(xb, Bt, m0, n0, smem, smem + 16384, acc);
  const int lane = threadIdx.x & 63;
  const int l15 = lane & 15, lg = lane >> 4;
  const int wm = (threadIdx.x >> 6) >> 1, wn = (threadIdx.x >> 6) & 1;
#pragma unroll
  for (int mf = 0; mf < 4; ++mf)
#pragma unroll
    for (int nf = 0; nf < 4; ++nf)
#pragma unroll
      for (int r = 0; r < 4; ++r) {
        const int row = m0 + wm * 64 + mf * 16 + lg * 4 + r;
        const int col = n0 + wn * 64 + nf * 16 + l15;
        C[(size_t)row * 1024 + col] = f2bf(acc[mf][nf][r] * oscale);
      }
}

// ---- output projection + bias, fp32 out ----
__global__ __launch_bounds__(256) void k_oproj(const unsigned short* __restrict__ ctx,
                                               const unsigned short* __restrict__ wot,
                                               const float* __restrict__ bo,
                                               float* __restrict__ outp) {
  __shared__ __align__(16) char smem[32768];
  const int m0 = blockIdx.x * 128, n0 = blockIdx.y * 128;
  f4v acc[4][4];
  f4v z = {0.f, 0.f, 0.f, 0.f};
#pragma unroll
  for (int a = 0; a < 4; ++a)
#pragma unroll
    for (int b = 0; b < 4; ++b) acc[a][b] = z;
  gemm_loop(ctx, wot, m0, n0, smem, smem + 16384, acc);
  const int lane = threadIdx.x & 63;
  const int l15 = lane & 15, lg = lane >> 4;
  const int wm = (threadIdx.x >> 6) >> 1, wn = (threadIdx.x >> 6) & 1;
#pragma unroll
  for (int nf = 0; nf < 4; ++nf) {
    const int col = n0 + wn * 64 + nf * 16 + l15;
    const float bias = bo[col];
#pragma unroll
    for (int mf = 0; mf < 4; ++mf)
#pragma unroll
      for (int r = 0; r < 4; ++r) {
        const int row = m0 + wm * 64 + mf * 16 + lg * 4 + r;
        outp[(size_t)row * 1024 + col] = acc[mf][nf][r] + bias;
      }
  }
}

// ---- V -> V^T per head: [B,S,H,64] -> [B,H,64,S] ----
__global__ __launch_bounds__(256) void k_tv(const unsigned short* __restrict__ v,
                                            unsigned short* __restrict__ vt) {
  __shared__ unsigned short tile[64][65];
  const int b = blockIdx.z, h = blockIdx.y, s0 = blockIdx.x * 64;
  const int t = threadIdx.x;
#pragma unroll
  for (int i = 0; i < 16; ++i) {
    const int s = i * 4 + (t >> 6), d = t & 63;
    tile[s][d] = v[(size_t)(b * SEQ + s0 + s) * 1024 + h * 64 + d];
  }
  __syncthreads();
#pragma unroll
  for (int i = 0; i < 16; ++i) {
    const int d = i * 4 + (t >> 6), s = t & 63;
    vt[(size_t)((b * NH + h) * 64 + d) * SEQ + s0 + s] = tile[s][d];
  }
}

// ---- stage one 64-kv tile of K [64kv][64d] and V^T [64d][64kv] into LDS ----
DEVINL void stage_kv(const unsigned short* __restrict__ kbase,
                     const unsigned short* __restrict__ vbase,
                     int kv0, char* Ks, char* Vs, int tid) {
#pragma unroll
  for (int i = 0; i < 2; ++i) {
    const int c = i * 256 + tid;
    const int row = c >> 3;
    const int csw = ((c & 7) ^ (row & 7)) * 8;
    gl_lds16(kbase + (size_t)(kv0 + row) * 1024 + csw, Ks + c * 16);
    gl_lds16(vbase + (size_t)row * SEQ + kv0 + csw, Vs + c * 16);
  }
}

// ---- causal flash attention: 4 waves x 32 q-rows, KVBLK=64, swapped-QK 32x32,
//      in-register softmax (lane owns one q-row), cvt_pk+permlane32_swap P->frag ----
__global__ __launch_bounds__(256) void k_attn(const unsigned short* __restrict__ q,
                                              const unsigned short* __restrict__ kg,
                                              const unsigned short* __restrict__ vt,
                                              unsigned short* __restrict__ ctx) {
  __shared__ __align__(16) char smem[32768];
  const int b = blockIdx.z, h = blockIdx.y, pair = blockIdx.x;
  const int tid = threadIdx.x, lane = tid & 63, w = tid >> 6;
  const int l31 = lane & 31, hi = lane >> 5;

  const unsigned short* kbase = kg + (size_t)b * SEQ * 1024 + h * 64;
  const unsigned short* vbase = vt + (size_t)((b * NH + h) * 64) * SEQ;

  f16v z16;
#pragma unroll
  for (int i = 0; i < 16; ++i) z16[i] = 0.f;

  for (int seg = 0; seg < 2; ++seg) {
    const int qi = seg == 0 ? pair : 15 - pair;
    const int qbb = qi * 128;
    const int qg = qbb + w * 32 + l31;  // this lane's q row (global)
    const unsigned short* qp = q + (size_t)(b * SEQ + qg) * 1024 + h * 64;
    s8v qf[4];
#pragma unroll
    for (int kd = 0; kd < 4; ++kd) qf[kd] = *(const s8v*)(qp + kd * 16 + hi * 8);

    f16v o0 = z16, o1 = z16;
    float m = -3e38f, lsum = 0.f;
    const int nt = qi * 2 + 2;

    __syncthreads();  // previous segment's reads complete
    stage_kv(kbase, vbase, 0, smem, smem + 16384, tid);

    for (int t = 0; t < nt; ++t) {
      const int kv0 = t * 64;
      char* Ks = smem + (t & 1) * 8192;
      char* Vs = smem + 16384 + (t & 1) * 8192;
      __syncthreads();  // staging of tile t complete
      if (t + 1 < nt)
        stage_kv(kbase, vbase, kv0 + 64, smem + ((t + 1) & 1) * 8192,
                 smem + 16384 + ((t + 1) & 1) * 8192, tid);
      if (kv0 > qbb + w * 32 + 31) continue;  // fully-masked tile for this warp

      // QK^T swapped: S^T[kv][q], col=q=lane&31
      f16v s0 = z16, s1 = z16;
#pragma unroll
      for (int kd = 0; kd < 4; ++kd) {
        const int off = kd * 32 + hi * 16;
        const int r0 = l31, r1 = 32 + l31;
        const s8v kf0 = *(const s8v*)(Ks + r0 * 128 + (off ^ ((r0 & 7) << 4)));
        const s8v kf1 = *(const s8v*)(Ks + r1 * 128 + (off ^ ((r1 & 7) << 4)));
        s0 = mfma32(kf0, qf[kd], s0);
        s1 = mfma32(kf1, qf[kd], s1);
      }

      // mask + row max (in-register; Q pre-scaled to log2 domain)
      const bool needmask = (kv0 + 63 > qbb + w * 32);
      const int crel = qg - kv0;
      float tmax = -3e38f;
#pragma unroll
      for (int r = 0; r < 16; ++r) {
        const int kvloc = (r & 3) + 8 * (r >> 2) + 4 * hi;
        float v0 = s0[r], v1 = s1[r];
        if (needmask) {
          if (kvloc > crel) v0 = -3e38f;
          if (kvloc + 32 > crel) v1 = -3e38f;
        }
        s0[r] = v0; s1[r] = v1;
        tmax = fmaxf(tmax, fmaxf(v0, v1));
      }
      tmax = fmaxf(tmax, __shfl_xor(tmax, 32));

      // T13 defer-max: per-lane (each lane owns its q-row)
      const bool grew = tmax > m + 8.f;
      const float mnew = grew ? tmax : m;
      const float corr = __builtin_amdgcn_exp2f(m - mnew);
      m = mnew;

      float rs = 0.f;
#pragma unroll
      for (int r = 0; r < 16; ++r) {
        const float e0 = __builtin_amdgcn_exp2f(s0[r] - m);
        const float e1 = __builtin_amdgcn_exp2f(s1[r] - m);
        s0[r] = e0; s1[r] = e1;
        rs += e0 + e1;
      }
      rs += __shfl_xor(rs, 32);
      lsum = lsum * corr + rs;
      if (__any(grew)) { o0 *= corr; o1 *= corr; }

      // P -> bf16 B-frags via cvt_pk + permlane32_swap
      unsigned a0 = cvtpk(s0[0], s0[1]), b0 = cvtpk(s0[4], s0[5]); plswap(a0, b0);
      unsigned a1 = cvtpk(s0[2], s0[3]), b1 = cvtpk(s0[6], s0[7]); plswap(a1, b1);
      const s8v f0 = mkfrag(a0, a1, b0, b1);
      unsigned a2 = cvtpk(s0[8], s0[9]), b2 = cvtpk(s0[12], s0[13]); plswap(a2, b2);
      unsigned a3 = cvtpk(s0[10], s0[11]), b3 = cvtpk(s0[14], s0[15]); plswap(a3, b3);
      const s8v f1 = mkfrag(a2, a3, b2, b3);
      unsigned a4 = cvtpk(s1[0], s1[1]), b4 = cvtpk(s1[4], s1[5]); plswap(a4, b4);
      unsigned a5 = cvtpk(s1[2], s1[3]), b5 = cvtpk(s1[6], s1[7]); plswap(a5, b5);
      const s8v f2 = mkfrag(a4, a5, b4, b5);
      unsigned a6 = cvtpk(s1[8], s1[9]), b6 = cvtpk(s1[12], s1[13]); plswap(a6, b6);
      unsigned a7 = cvtpk(s1[10], s1[11]), b7 = cvtpk(s1[14], s1[15]); plswap(a7, b7);
      const s8v f3 = mkfrag(a6, a7, b6, b7);

      // PV: O^T[d][q] += V^T-frag x P-frag
#pragma unroll
      for (int ks = 0; ks < 4; ++ks) {
        const s8v pb = ks == 0 ? f0 : ks == 1 ? f1 : ks == 2 ? f2 : f3;
        const int off = ks * 32 + hi * 16;
        const int rd0 = l31, rd1 = 32 + l31;
        const s8v v0 = *(const s8v*)(Vs + rd0 * 128 + (off ^ ((rd0 & 7) << 4)));
        const s8v v1 = *(const s8v*)(Vs + rd1 * 128 + (off ^ ((rd1 & 7) << 4)));
        o0 = mfma32(v0, pb, o0);
        o1 = mfma32(v1, pb, o1);
      }
    }

    // epilogue: lane owns q-row qg; d = crow(r)+4*hi (+32 for o1)
    const float rl = 1.f / lsum;
    unsigned short* crow_p = ctx + (size_t)(b * SEQ + qg) * 1024 + h * 64;
#pragma unroll
    for (int r = 0; r < 16; ++r) {
      const int d = (r & 3) + 8 * (r >> 2) + 4 * hi;
      crow_p[d] = f2bf(o0[r] * rl);
      crow_p[32 + d] = f2bf(o1[r] * rl);
    }
  }
}

extern "C" void kernel_launch(void* const* d_in, const int* in_sizes, int n_in,
                              void* d_out, int out_size, void* d_ws, size_t ws_size,
                              hipStream_t stream) {
  (void)in_sizes; (void)n_in; (void)out_size; (void)ws_size;
  const float* x = (const float*)d_in[0];
  const float* wq = (const float*)d_in[1];
  const float* wk = (const float*)d_in[2];
  const float* wv = (const float*)d_in[3];
  const float* wo = (const float*)d_in[4];
  const float* bo = (const float*)d_in[5];
  float* outp = (float*)d_out;
  char* ws = (char*)d_ws;
  const size_t MB = 1ull << 20;
  unsigned short* xb  = (unsigned short*)(ws + 0 * MB);
  unsigned short* wqt = (unsigned short*)(ws + 16 * MB);
  unsigned short* wkt = (unsigned short*)(ws + 18 * MB);
  unsigned short* wvt = (unsigned short*)(ws + 20 * MB);
  unsigned short* wot = (unsigned short*)(ws + 22 * MB);
  unsigned short* qb_ = (unsigned short*)(ws + 24 * MB);
  unsigned short* kb_ = (unsigned short*)(ws + 40 * MB);
  unsigned short* vb_ = (unsigned short*)(ws + 56 * MB);
  unsigned short* vtb = (unsigned short*)(ws + 72 * MB);
  unsigned short* ctx = (unsigned short*)(ws + 88 * MB);

  k_cvt<<<4096, 256, 0, stream>>>(x, xb);
  k_twt<<<dim3(32, 32, 4), 256, 0, stream>>>(wq, wk, wv, wo, wqt, wkt, wvt, wot);
  k_qkv<<<dim3(64, 24), 256, 0, stream>>>(xb, wqt, wkt, wvt, qb_, kb_, vb_);
  k_tv<<<dim3(32, 16, 4), 256, 0, stream>>>(vb_, vtb);
  k_attn<<<dim3(8, 16, 4), 256, 0, stream>>>(qb_, kb_, vtb, ctx);
  k_oproj<<<dim3(64, 8), 256, 0, stream>>>(ctx, wot, bo, outp);
}

// Round 5
// 256.099 us; speedup vs baseline: 1.7616x; 1.0176x over previous
//
#include <hip/hip_runtime.h>

#define DEVINL __device__ __forceinline__

typedef __attribute__((ext_vector_type(8))) short s8v;
typedef __attribute__((ext_vector_type(4))) float f4v;
typedef __attribute__((ext_vector_type(16))) float f16v;
typedef __attribute__((ext_vector_type(8))) __bf16 bf8v;
typedef __attribute__((ext_vector_type(4))) unsigned int u4v;

// Problem constants
static constexpr int SEQ = 2048;
static constexpr int DIM = 1024;
static constexpr int NH = 16;

DEVINL unsigned short f2bf(float f) {
  unsigned int u = __builtin_bit_cast(unsigned int, f);
  u += 0x7FFFu + ((u >> 16) & 1u);   // RNE
  return (unsigned short)(u >> 16);
}

DEVINL void gl_lds16(const void* g, void* l) {
  __builtin_amdgcn_global_load_lds((__attribute__((address_space(1))) void*)g,
                                   (__attribute__((address_space(3))) void*)l,
                                   16, 0, 0);
}

DEVINL f4v mfma16(s8v a, s8v b, f4v c) {
  return __builtin_amdgcn_mfma_f32_16x16x32_bf16(__builtin_bit_cast(bf8v, a),
                                                 __builtin_bit_cast(bf8v, b),
                                                 c, 0, 0, 0);
}

DEVINL f16v mfma32(s8v a, s8v b, f16v c) {
  return __builtin_amdgcn_mfma_f32_32x32x16_bf16(__builtin_bit_cast(bf8v, a),
                                                 __builtin_bit_cast(bf8v, b),
                                                 c, 0, 0, 0);
}

DEVINL unsigned cvtpk(float lo, float hi) {
  unsigned r;
  asm("v_cvt_pk_bf16_f32 %0, %1, %2" : "=v"(r) : "v"(lo), "v"(hi));
  return r;
}

DEVINL void plswap(unsigned& a, unsigned& b) {
#if __has_builtin(__builtin_amdgcn_permlane32_swap)
  typedef int i2v __attribute__((ext_vector_type(2)));
  i2v r = __builtin_amdgcn_permlane32_swap((int)a, (int)b, false, false);
  a = (unsigned)r[0]; b = (unsigned)r[1];
#else
  asm volatile("v_permlane32_swap_b32 %0, %1" : "+v"(a), "+v"(b));
#endif
}

DEVINL s8v mkfrag(unsigned w0, unsigned w1, unsigned w2, unsigned w3) {
  u4v t = {w0, w1, w2, w3};
  return __builtin_bit_cast(s8v, t);
}

// ---- x: fp32 -> bf16, 8 elems/thread ----
__global__ __launch_bounds__(256) void k_cvt(const float* __restrict__ in,
                                             unsigned short* __restrict__ outp) {
  const int i = blockIdx.x * 256 + threadIdx.x;
  const f4v* p = (const f4v*)in + (size_t)i * 2;
  f4v a = p[0], b = p[1];
  s8v o;
  o[0] = (short)f2bf(a[0]); o[1] = (short)f2bf(a[1]);
  o[2] = (short)f2bf(a[2]); o[3] = (short)f2bf(a[3]);
  o[4] = (short)f2bf(b[0]); o[5] = (short)f2bf(b[1]);
  o[6] = (short)f2bf(b[2]); o[7] = (short)f2bf(b[3]);
  ((s8v*)outp)[i] = o;
}

// ---- weight transpose: fp32 [K][N] -> bf16 [N][K] ----
__global__ __launch_bounds__(256) void k_twt(const float* __restrict__ w0, const float* __restrict__ w1,
                                             const float* __restrict__ w2, const float* __restrict__ w3,
                                             unsigned short* __restrict__ o0, unsigned short* __restrict__ o1,
                                             unsigned short* __restrict__ o2, unsigned short* __restrict__ o3) {
  __shared__ float tile[32][33];
  const float* w = blockIdx.z == 0 ? w0 : blockIdx.z == 1 ? w1 : blockIdx.z == 2 ? w2 : w3;
  unsigned short* o = blockIdx.z == 0 ? o0 : blockIdx.z == 1 ? o1 : blockIdx.z == 2 ? o2 : o3;
  const int r0 = blockIdx.y * 32, c0 = blockIdx.x * 32;
  const int tx = threadIdx.x & 31, ty = threadIdx.x >> 5;
#pragma unroll
  for (int i = 0; i < 32; i += 8) tile[ty + i][tx] = w[(r0 + ty + i) * DIM + c0 + tx];
  __syncthreads();
#pragma unroll
  for (int i = 0; i < 32; i += 8) o[(c0 + ty + i) * DIM + r0 + tx] = f2bf(tile[tx][ty + i]);
}

// ==== 128x128xBK64 GEMM, 2-buffer LDS ring, counted vmcnt(8), raw s_barrier ====
// LDS 64KB static: A bufs 2 x [128][64] bf16 (16KB) at 0/16K; B bufs at 32K/48K.
// Stage = 8 global_load_lds_dwordx4 per thread (4 A + 4 B). Prefetch distance 1:
// stage(t+1) targets the buffer tile t-1 vacated at the previous end-of-tile barrier.
// vmcnt(8) at tile t's head => tile t's 8 loads landed; t+1's 8 stay in flight.
DEVINL void stage128(const unsigned short* __restrict__ A, const unsigned short* __restrict__ Bt,
                     int m0, int n0, int k0, char* Ab, char* Bb, int tid) {
#pragma unroll
  for (int ld = 0; ld < 4; ++ld) {
    const int c = ld * 256 + tid;
    const int row = c >> 3;
    const int csw = ((c & 7) ^ (row & 7)) * 8;
    gl_lds16(A + (size_t)(m0 + row) * 1024 + k0 + csw, Ab + c * 16);
    gl_lds16(Bt + (size_t)(n0 + row) * 1024 + k0 + csw, Bb + c * 16);
  }
}

DEVINL void gemm_compute_tile(char* Ar, char* Br, f4v acc[4][4],
                              int l15, int lg, int wm, int wn) {
#pragma unroll
  for (int kk = 0; kk < 2; ++kk) {
    s8v af[4], bfr[4];
    const int kb2 = (kk * 32 + lg * 8) * 2;
#pragma unroll
    for (int mf = 0; mf < 4; ++mf) {
      const int row = wm * 64 + mf * 16 + l15;
      af[mf] = *(const s8v*)(Ar + row * 128 + (kb2 ^ ((row & 7) << 4)));
    }
#pragma unroll
    for (int nf = 0; nf < 4; ++nf) {
      const int row = wn * 64 + nf * 16 + l15;
      bfr[nf] = *(const s8v*)(Br + row * 128 + (kb2 ^ ((row & 7) << 4)));
    }
#pragma unroll
    for (int mf = 0; mf < 4; ++mf)
#pragma unroll
      for (int nf = 0; nf < 4; ++nf) acc[mf][nf] = mfma16(af[mf], bfr[nf], acc[mf][nf]);
  }
}

DEVINL void gemm_ring(const unsigned short* __restrict__ A, const unsigned short* __restrict__ Bt,
                      int m0, int n0, char* smem, f4v acc[4][4]) {
  const int tid = threadIdx.x;
  const int lane = tid & 63, l15 = lane & 15, lg = lane >> 4;
  const int wm = (tid >> 6) >> 1, wn = (tid >> 6) & 1;
  constexpr int NT = 16;  // K=1024 / BK=64

  stage128(A, Bt, m0, n0, 0, smem, smem + 32768, tid);  // tile 0 -> buf 0

  for (int t = 0; t < NT - 1; ++t) {
    const int nb = (t + 1) & 1;
    stage128(A, Bt, m0, n0, (t + 1) * 64, smem + nb * 16384, smem + 32768 + nb * 16384, tid);
    asm volatile("s_waitcnt vmcnt(8)" ::: "memory");  // tile t landed; t+1 in flight
    __builtin_amdgcn_s_barrier();
    __builtin_amdgcn_sched_barrier(0);
    const int cb = t & 1;
    gemm_compute_tile(smem + cb * 16384, smem + 32768 + cb * 16384, acc, l15, lg, wm, wn);
    asm volatile("s_waitcnt lgkmcnt(0)" ::: "memory");  // this wave done reading buf t
    __builtin_amdgcn_sched_barrier(0);
    __builtin_amdgcn_s_barrier();                        // buf t reusable by staging
  }
  // final tile (NT-1): nothing left to stage
  asm volatile("s_waitcnt vmcnt(0)" ::: "memory");
  __builtin_amdgcn_s_barrier();
  __builtin_amdgcn_sched_barrier(0);
  gemm_compute_tile(smem + ((NT - 1) & 1) * 16384, smem + 32768 + ((NT - 1) & 1) * 16384,
                    acc, l15, lg, wm, wn);
}

// ---- QKV projection: 1536 blocks, XCD-bijective swizzle; A-panel-hot ordering ----
__global__ __launch_bounds__(256) void k_qkv(const unsigned short* __restrict__ xb,
                                             const unsigned short* __restrict__ wqt,
                                             const unsigned short* __restrict__ wkt,
                                             const unsigned short* __restrict__ wvt,
                                             unsigned short* __restrict__ q,
                                             unsigned short* __restrict__ k,
                                             unsigned short* __restrict__ v) {
  __shared__ __align__(16) char smem[65536];
  const int wgid = (blockIdx.x & 7) * 192 + (blockIdx.x >> 3);  // bijective: 1536 % 8 == 0
  const int m0 = (wgid / 24) * 128;
  const int rem = wgid % 24;
  const int which = rem >> 3;
  const int n0 = (rem & 7) * 128;
  const unsigned short* Bt = which == 0 ? wqt : which == 1 ? wkt : wvt;
  unsigned short* C = which == 0 ? q : which == 1 ? k : v;
  const float oscale = which == 0 ? 0.125f * 1.44269504f : 1.0f;
  f4v acc[4][4];
  const f4v z = {0.f, 0.f, 0.f, 0.f};
#pragma unroll
  for (int a = 0; a < 4; ++a)
#pragma unroll
    for (int b = 0; b < 4; ++b) acc[a][b] = z;
  gemm_ring(xb, Bt, m0, n0, smem, acc);
  const int lane = threadIdx.x & 63, l15 = lane & 15, lg = lane >> 4;
  const int wm = (threadIdx.x >> 6) >> 1, wn = (threadIdx.x >> 6) & 1;
#pragma unroll
  for (int mf = 0; mf < 4; ++mf)
#pragma unroll
    for (int nf = 0; nf < 4; ++nf)
#pragma unroll
      for (int r = 0; r < 4; ++r) {
        const int row = m0 + wm * 64 + mf * 16 + lg * 4 + r;
        const int col = n0 + wn * 64 + nf * 16 + l15;
        C[(size_t)row * 1024 + col] = f2bf(acc[mf][nf][r] * oscale);
      }
}

// ---- output projection + bias, fp32 out: 512 blocks, XCD-bijective swizzle ----
__global__ __launch_bounds__(256) void k_oproj(const unsigned short* __restrict__ ctx,
                                               const unsigned short* __restrict__ wot,
                                               const float* __restrict__ bo,
                                               float* __restrict__ outp) {
  __shared__ __align__(16) char smem[65536];
  const int wgid = (blockIdx.x & 7) * 64 + (blockIdx.x >> 3);  // bijective: 512 % 8 == 0
  const int m0 = (wgid >> 3) * 128;
  const int n0 = (wgid & 7) * 128;
  f4v acc[4][4];
  const f4v z = {0.f, 0.f, 0.f, 0.f};
#pragma unroll
  for (int a = 0; a < 4; ++a)
#pragma unroll
    for (int b = 0; b < 4; ++b) acc[a][b] = z;
  gemm_ring(ctx, wot, m0, n0, smem, acc);
  const int lane = threadIdx.x & 63, l15 = lane & 15, lg = lane >> 4;
  const int wm = (threadIdx.x >> 6) >> 1, wn = (threadIdx.x >> 6) & 1;
#pragma unroll
  for (int nf = 0; nf < 4; ++nf) {
    const int col = n0 + wn * 64 + nf * 16 + l15;
    const float bias = bo[col];
#pragma unroll
    for (int mf = 0; mf < 4; ++mf)
#pragma unroll
      for (int r = 0; r < 4; ++r) {
        const int row = m0 + wm * 64 + mf * 16 + lg * 4 + r;
        outp[(size_t)row * 1024 + col] = acc[mf][nf][r] + bias;
      }
  }
}

// ---- V -> V^T per head: [B,S,H,64] -> [B,H,64,S] ----
__global__ __launch_bounds__(256) void k_tv(const unsigned short* __restrict__ v,
                                            unsigned short* __restrict__ vt) {
  __shared__ unsigned short tile[64][65];
  const int b = blockIdx.z, h = blockIdx.y, s0 = blockIdx.x * 64;
  const int t = threadIdx.x;
#pragma unroll
  for (int i = 0; i < 16; ++i) {
    const int s = i * 4 + (t >> 6), d = t & 63;
    tile[s][d] = v[(size_t)(b * SEQ + s0 + s) * 1024 + h * 64 + d];
  }
  __syncthreads();
#pragma unroll
  for (int i = 0; i < 16; ++i) {
    const int d = i * 4 + (t >> 6), s = t & 63;
    vt[(size_t)((b * NH + h) * 64 + d) * SEQ + s0 + s] = tile[s][d];
  }
}

// ---- stage one 64-kv tile of K [64kv][64d] and V^T [64d][64kv] into LDS ----
DEVINL void stage_kv(const unsigned short* __restrict__ kbase,
                     const unsigned short* __restrict__ vbase,
                     int kv0, char* Ks, char* Vs, int tid) {
#pragma unroll
  for (int i = 0; i < 2; ++i) {
    const int c = i * 256 + tid;
    const int row = c >> 3;
    const int csw = ((c & 7) ^ (row & 7)) * 8;
    gl_lds16(kbase + (size_t)(kv0 + row) * 1024 + csw, Ks + c * 16);
    gl_lds16(vbase + (size_t)row * SEQ + kv0 + csw, Vs + c * 16);
  }
}

// ---- causal flash attention: 4 waves x 32 q-rows, KVBLK=64, swapped-QK 32x32,
//      in-register softmax, cvt_pk+permlane32_swap P->frag ----
__global__ __launch_bounds__(256) void k_attn(const unsigned short* __restrict__ q,
                                              const unsigned short* __restrict__ kg,
                                              const unsigned short* __restrict__ vt,
                                              unsigned short* __restrict__ ctx) {
  __shared__ __align__(16) char smem[32768];
  const int b = blockIdx.z, h = blockIdx.y, pair = blockIdx.x;
  const int tid = threadIdx.x, lane = tid & 63, w = tid >> 6;
  const int l31 = lane & 31, hi = lane >> 5;

  const unsigned short* kbase = kg + (size_t)b * SEQ * 1024 + h * 64;
  const unsigned short* vbase = vt + (size_t)((b * NH + h) * 64) * SEQ;

  f16v z16;
#pragma unroll
  for (int i = 0; i < 16; ++i) z16[i] = 0.f;

  for (int seg = 0; seg < 2; ++seg) {
    const int qi = seg == 0 ? pair : 15 - pair;
    const int qbb = qi * 128;
    const int qg = qbb + w * 32 + l31;
    const unsigned short* qp = q + (size_t)(b * SEQ + qg) * 1024 + h * 64;
    s8v qf[4];
#pragma unroll
    for (int kd = 0; kd < 4; ++kd) qf[kd] = *(const s8v*)(qp + kd * 16 + hi * 8);

    f16v o0 = z16, o1 = z16;
    float m = -3e38f, lsum = 0.f;
    const int nt = qi * 2 + 2;

    __syncthreads();
    stage_kv(kbase, vbase, 0, smem, smem + 16384, tid);

    for (int t = 0; t < nt; ++t) {
      const int kv0 = t * 64;
      char* Ks = smem + (t & 1) * 8192;
      char* Vs = smem + 16384 + (t & 1) * 8192;
      __syncthreads();
      if (t + 1 < nt)
        stage_kv(kbase, vbase, kv0 + 64, smem + ((t + 1) & 1) * 8192,
                 smem + 16384 + ((t + 1) & 1) * 8192, tid);
      if (kv0 > qbb + w * 32 + 31) continue;

      f16v s0 = z16, s1 = z16;
#pragma unroll
      for (int kd = 0; kd < 4; ++kd) {
        const int off = kd * 32 + hi * 16;
        const int r0 = l31, r1 = 32 + l31;
        const s8v kf0 = *(const s8v*)(Ks + r0 * 128 + (off ^ ((r0 & 7) << 4)));
        const s8v kf1 = *(const s8v*)(Ks + r1 * 128 + (off ^ ((r1 & 7) << 4)));
        s0 = mfma32(kf0, qf[kd], s0);
        s1 = mfma32(kf1, qf[kd], s1);
      }

      const bool needmask = (kv0 + 63 > qbb + w * 32);
      const int crel = qg - kv0;
      float tmax = -3e38f;
#pragma unroll
      for (int r = 0; r < 16; ++r) {
        const int kvloc = (r & 3) + 8 * (r >> 2) + 4 * hi;
        float v0 = s0[r], v1 = s1[r];
        if (needmask) {
          if (kvloc > crel) v0 = -3e38f;
          if (kvloc + 32 > crel) v1 = -3e38f;
        }
        s0[r] = v0; s1[r] = v1;
        tmax = fmaxf(tmax, fmaxf(v0, v1));
      }
      tmax = fmaxf(tmax, __shfl_xor(tmax, 32));

      const bool grew = tmax > m + 8.f;
      const float mnew = grew ? tmax : m;
      const float corr = __builtin_amdgcn_exp2f(m - mnew);
      m = mnew;

      float rs = 0.f;
#pragma unroll
      for (int r = 0; r < 16; ++r) {
        const float e0 = __builtin_amdgcn_exp2f(s0[r] - m);
        const float e1 = __builtin_amdgcn_exp2f(s1[r] - m);
        s0[r] = e0; s1[r] = e1;
        rs += e0 + e1;
      }
      rs += __shfl_xor(rs, 32);
      lsum = lsum * corr + rs;
      if (__any(grew)) { o0 *= corr; o1 *= corr; }

      unsigned a0 = cvtpk(s0[0], s0[1]), b0 = cvtpk(s0[4], s0[5]); plswap(a0, b0);
      unsigned a1 = cvtpk(s0[2], s0[3]), b1 = cvtpk(s0[6], s0[7]); plswap(a1, b1);
      const s8v f0 = mkfrag(a0, a1, b0, b1);
      unsigned a2 = cvtpk(s0[8], s0[9]), b2 = cvtpk(s0[12], s0[13]); plswap(a2, b2);
      unsigned a3 = cvtpk(s0[10], s0[11]), b3 = cvtpk(s0[14], s0[15]); plswap(a3, b3);
      const s8v f1 = mkfrag(a2, a3, b2, b3);
      unsigned a4 = cvtpk(s1[0], s1[1]), b4 = cvtpk(s1[4], s1[5]); plswap(a4, b4);
      unsigned a5 = cvtpk(s1[2], s1[3]), b5 = cvtpk(s1[6], s1[7]); plswap(a5, b5);
      const s8v f2 = mkfrag(a4, a5, b4, b5);
      unsigned a6 = cvtpk(s1[8], s1[9]), b6 = cvtpk(s1[12], s1[13]); plswap(a6, b6);
      unsigned a7 = cvtpk(s1[10], s1[11]), b7 = cvtpk(s1[14], s1[15]); plswap(a7, b7);
      const s8v f3 = mkfrag(a6, a7, b6, b7);

#pragma unroll
      for (int ks = 0; ks < 4; ++ks) {
        const s8v pb = ks == 0 ? f0 : ks == 1 ? f1 : ks == 2 ? f2 : f3;
        const int off = ks * 32 + hi * 16;
        const int rd0 = l31, rd1 = 32 + l31;
        const s8v v0 = *(const s8v*)(Vs + rd0 * 128 + (off ^ ((rd0 & 7) << 4)));
        const s8v v1 = *(const s8v*)(Vs + rd1 * 128 + (off ^ ((rd1 & 7) << 4)));
        o0 = mfma32(v0, pb, o0);
        o1 = mfma32(v1, pb, o1);
      }
    }

    const float rl = 1.f / lsum;
    unsigned short* crow_p = ctx + (size_t)(b * SEQ + qg) * 1024 + h * 64;
#pragma unroll
    for (int r = 0; r < 16; ++r) {
      const int d = (r & 3) + 8 * (r >> 2) + 4 * hi;
      crow_p[d] = f2bf(o0[r] * rl);
      crow_p[32 + d] = f2bf(o1[r] * rl);
    }
  }
}

extern "C" void kernel_launch(void* const* d_in, const int* in_sizes, int n_in,
                              void* d_out, int out_size, void* d_ws, size_t ws_size,
                              hipStream_t stream) {
  (void)in_sizes; (void)n_in; (void)out_size; (void)ws_size;
  const float* x = (const float*)d_in[0];
  const float* wq = (const float*)d_in[1];
  const float* wk = (const float*)d_in[2];
  const float* wv = (const float*)d_in[3];
  const float* wo = (const float*)d_in[4];
  const float* bo = (const float*)d_in[5];
  float* outp = (float*)d_out;
  char* ws = (char*)d_ws;
  const size_t MB = 1ull << 20;
  unsigned short* xb  = (unsigned short*)(ws + 0 * MB);
  unsigned short* wqt = (unsigned short*)(ws + 16 * MB);
  unsigned short* wkt = (unsigned short*)(ws + 18 * MB);
  unsigned short* wvt = (unsigned short*)(ws + 20 * MB);
  unsigned short* wot = (unsigned short*)(ws + 22 * MB);
  unsigned short* qb_ = (unsigned short*)(ws + 24 * MB);
  unsigned short* kb_ = (unsigned short*)(ws + 40 * MB);
  unsigned short* vb_ = (unsigned short*)(ws + 56 * MB);
  unsigned short* vtb = (unsigned short*)(ws + 72 * MB);
  unsigned short* ctx = (unsigned short*)(ws + 88 * MB);

  k_cvt<<<4096, 256, 0, stream>>>(x, xb);
  k_twt<<<dim3(32, 32, 4), 256, 0, stream>>>(wq, wk, wv, wo, wqt, wkt, wvt, wot);
  k_qkv<<<1536, 256, 0, stream>>>(xb, wqt, wkt, wvt, qb_, kb_, vb_);
  k_tv<<<dim3(32, 16, 4), 256, 0, stream>>>(vb_, vtb);
  k_attn<<<dim3(8, 16, 4), 256, 0, stream>>>(qb_, kb_, vtb, ctx);
  k_oproj<<<512, 256, 0, stream>>>(ctx, wot, bo, outp);
}